// Round 16
// baseline (169.303 us; speedup 1.0000x reference)
//
#include <hip/hip_runtime.h>

// LRN: out[c] = x[c] / sqrt( sum_{i=max(0,c-128)}^{min(255,c+127)} x[i]^2 )
// (ALPHA/N = 1.0, K = 0, BETA = 0.5, ch = N = 256, half_n = 128)
//
// Measured history (lrn_kernel dispatch time; scored dur in parens):
//   r2 : shfl-scan (bpermute), plain ld/st ............ 61.5 us
//   r6 : + ILP x4, nt loads, nt stores ................ ~54 us  (171.2)
//   r7 : ILP x4, plain loads, nt stores ............... 61.2 us (177.8)
//        -> nt loads are the win; ILP alone ~0.
//   r8 : DPP scan w/ wrong row_masks + permlane asm ... NaN FAIL
//   r10: r6 + canonical DPP scan ...................... ~52 us  (169.3)
//        -> scan chain was only ~2us; residual is VALU mass / latency.
// r11 edit (single change): IEEE sqrt+div epilogue -> v_rsq_f32 + v_mul.
//   Safe: ws >= x_c^2 -> |out| <= 1; rsq rel err ~2^-22 -> abs err ~5e-7,
//   harness compares at bf16 (threshold 8.59e-3, our absmax 2^-10 = bf16
//   rounding floor). Cuts ~350 VALU instrs/wave to ~32.
//
// Window lookups (verified at c=0,125..130,255):
//   c <= 128 : ws = incl[c+127]    c >= 129 : ws = total - incl[c-129]
//   j=0: src lane (l+31)&63, elem 3 (both branches)
//   j=1..3: src lane l^32, elem j-1 (both branches)

#define PIX 4

typedef float f32x4 __attribute__((ext_vector_type(4)));

// One scan step: s += dpp_moved(s); invalid/masked lanes contribute old=0.
template <int CTRL, int ROWMASK>
__device__ __forceinline__ float dppAdd(float s) {
    int t = __builtin_amdgcn_update_dpp(0, __float_as_int(s), CTRL, ROWMASK,
                                        0xF, false);
    return s + __int_as_float(t);
}

__global__ __launch_bounds__(256) void lrn_kernel(const float* __restrict__ x,
                                                  float* __restrict__ out,
                                                  int npix) {
    const int lane = threadIdx.x & 63;
    const int wave = threadIdx.x >> 6;
    const int pbase = (blockIdx.x * 4 + wave) * PIX;
    if (pbase + PIX > npix) return;  // grid exact (100352/16=6272); never taken

    const f32x4* __restrict__ xv = reinterpret_cast<const f32x4*>(x);

    // nt loads (r6/r7 A/B: the measured win).
    f32x4 v[PIX];
#pragma unroll
    for (int p = 0; p < PIX; ++p) {
        const f32x4* src = xv + (size_t)(pbase + p) * 64 + lane;
        v[p] = __builtin_nontemporal_load(src);
    }

    float sx[PIX], sy[PIX], sz[PIX], sw[PIX], s4[PIX], s[PIX];
#pragma unroll
    for (int p = 0; p < PIX; ++p) {
        sx[p] = v[p].x * v[p].x;
        sy[p] = v[p].y * v[p].y;
        sz[p] = v[p].z * v[p].z;
        sw[p] = v[p].w * v[p].w;
        s4[p] = sx[p] + sy[p] + sz[p] + sw[p];
        s[p]  = s4[p];
    }

    // Canonical gfx9 wave64 inclusive scan, pure VALU (no LDS pipe):
    //   row_shr:1/2/4/8 (mask 0xF), row_bcast:15 (mask 0xa: rows 1,3),
    //   row_bcast:31 (mask 0xc: rows 2,3).  [rocPRIM warp_scan_dpp / LLVM]
#pragma unroll
    for (int p = 0; p < PIX; ++p) s[p] = dppAdd<0x111, 0xF>(s[p]);
#pragma unroll
    for (int p = 0; p < PIX; ++p) s[p] = dppAdd<0x112, 0xF>(s[p]);
#pragma unroll
    for (int p = 0; p < PIX; ++p) s[p] = dppAdd<0x114, 0xF>(s[p]);
#pragma unroll
    for (int p = 0; p < PIX; ++p) s[p] = dppAdd<0x118, 0xF>(s[p]);
#pragma unroll
    for (int p = 0; p < PIX; ++p) s[p] = dppAdd<0x142, 0xa>(s[p]);
#pragma unroll
    for (int p = 0; p < PIX; ++p) s[p] = dppAdd<0x143, 0xc>(s[p]);

    // total via readlane (SALU broadcast, off the LDS pipe).
    float total[PIX];
#pragma unroll
    for (int p = 0; p < PIX; ++p)
        total[p] = __uint_as_float(
            __builtin_amdgcn_readlane(__float_as_uint(s[p]), 63));

    // In-lane inclusive prefixes incl[4l+j].
    float i0[PIX], i1[PIX], i2[PIX], i3[PIX];
#pragma unroll
    for (int p = 0; p < PIX; ++p) {
        float pre = s[p] - s4[p];
        i0[p] = pre + sx[p];
        i1[p] = i0[p] + sy[p];
        i2[p] = i1[p] + sz[p];
        i3[p] = i2[p] + sw[p];
    }

    // Window-boundary gathers (__shfl/bpermute, 16 ops, mutually
    // independent -> one parallel latency).
    const int srcA = (lane + 31) & 63;
    const int srcB = lane ^ 32;
    float a3[PIX], b0[PIX], b1[PIX], b2[PIX];
#pragma unroll
    for (int p = 0; p < PIX; ++p) a3[p] = __shfl(i3[p], srcA, 64);
#pragma unroll
    for (int p = 0; p < PIX; ++p) b0[p] = __shfl(i0[p], srcB, 64);
#pragma unroll
    for (int p = 0; p < PIX; ++p) b1[p] = __shfl(i1[p], srcB, 64);
#pragma unroll
    for (int p = 0; p < PIX; ++p) b2[p] = __shfl(i2[p], srcB, 64);

    const bool lo0 = (lane <= 32);  // c=4l   <= 128
    const bool lo  = (lane <= 31);  // c=4l+j <= 128 for j>=1

    f32x4* __restrict__ ov = reinterpret_cast<f32x4*>(out);
#pragma unroll
    for (int p = 0; p < PIX; ++p) {
        float ws0 = lo0 ? a3[p] : (total[p] - a3[p]);
        float ws1 = lo  ? b0[p] : (total[p] - b0[p]);
        float ws2 = lo  ? b1[p] : (total[p] - b1[p]);
        float ws3 = lo  ? b2[p] : (total[p] - b2[p]);

        // r11: x * v_rsq_f32(ws). |out|<=1, rsq abs err ~5e-7 << 8.6e-3
        // bf16-compare threshold (measured absmax floor 2^-10).
        f32x4 o;
        o.x = v[p].x * __builtin_amdgcn_rsqf(ws0);
        o.y = v[p].y * __builtin_amdgcn_rsqf(ws1);
        o.z = v[p].z * __builtin_amdgcn_rsqf(ws2);
        o.w = v[p].w * __builtin_amdgcn_rsqf(ws3);

        // Output never re-read: nt store (no-allocate keeps input resident).
        f32x4* dst = ov + (size_t)(pbase + p) * 64 + lane;
        __builtin_nontemporal_store(o, dst);
    }
}

extern "C" void kernel_launch(void* const* d_in, const int* in_sizes, int n_in,
                              void* d_out, int out_size, void* d_ws, size_t ws_size,
                              hipStream_t stream) {
    const float* x = (const float*)d_in[0];
    float* out = (float*)d_out;
    int total = in_sizes[0];           // 32*56*56*256 = 25,690,112
    int npix = total / 256;            // 100,352 pixels

    // 16 pixels per block (4 waves x 4 pixels) -> 6272 blocks exactly.
    int blocks = (npix + 4 * PIX - 1) / (4 * PIX);
    lrn_kernel<<<blocks, 256, 0, stream>>>(x, out, npix);
}